// Round 11
// baseline (149.568 us; speedup 1.0000x reference)
//
#include <hip/hip_runtime.h>

// Problem constants
#define D    128      // d+1
#define DM   127      // d
#define NP1  1024     // N+1
#define B    8
#define H    8
#define NL   4
#define DD   (D*D)

typedef __attribute__((ext_vector_type(8))) __bf16 bf16x8;
typedef __attribute__((ext_vector_type(8))) unsigned short ushort8;
typedef __attribute__((ext_vector_type(4))) unsigned short ushort4v;
typedef __attribute__((ext_vector_type(4))) float f32x4;

// Workspace layout (float offsets), ~10.8 MB
#define WS_GP   0                           // [B][8][128][128] f32 Gram partials
#define WS_SPT  (WS_GP + B*8*DD)            // [B][H][128][128] bf16 S_h^T partials (swz)
#define WS_QB   (WS_SPT + B*H*DD/2)         // [NL][H] bf16 Qf (1/N folded), swz
#define WS_PB   (WS_QB + NL*H*DD/2)         // [NL][H] bf16 Pf (corner 1), swz
#define WS_GBF  (WS_PB + NL*H*DD/2)         // 2x [B] bf16 G swz (ping-pong)
#define WS_GF   (WS_GBF + 2*B*DD/2)         // 2x [B] f32 G row-major (ping-pong)
#define WS_RB   (WS_GF + 2*B*DD)            // 2x [B] bf16 R row-major swz (ping-pong)
#define WS_RTB  (WS_RB + 2*B*DD/2)          // [B] bf16 R^T swz (for zfinal)

__device__ __forceinline__ void async16(const void* g, void* l)
{
    __builtin_amdgcn_global_load_lds(
        (const __attribute__((address_space(1))) void*)g,
        (__attribute__((address_space(3))) void*)l,
        16, 0, 0);
}

__device__ __forceinline__ unsigned short f2bf(float f)
{
    unsigned int u = __float_as_uint(f);
    u += 0x7fffu + ((u >> 16) & 1u);
    return (unsigned short)(u >> 16);
}
__device__ __forceinline__ float bf2f(unsigned short v)
{
    return __uint_as_float((unsigned int)v << 16);
}
__device__ __forceinline__ int SW(int row, int col)   // bf16 [*][128] swizzle
{
    return row * 128 + (col ^ ((row & 7) << 3));
}
__device__ __forceinline__ bf16x8 fragAB(const unsigned short* Lb, int row0, int k0, int lane)
{
    const int r = row0 + (lane & 15);
    const int c = (k0 + ((lane >> 4) << 3)) ^ ((r & 7) << 3);
    union { ushort8 u; bf16x8 b; } U;
    U.u = *(const ushort8*)&Lb[r * 128 + c];
    return U.b;
}
__device__ __forceinline__ ushort4v packbf(f32x4 a)
{
    ushort4v v;
    v[0] = f2bf(a[0]); v[1] = f2bf(a[1]); v[2] = f2bf(a[2]); v[3] = f2bf(a[3]);
    return v;
}
#define MFMA(a, b, c) __builtin_amdgcn_mfma_f32_16x16x32_bf16((a), (b), (c), 0, 0, 0)

// ---------------------------------------------------------------------------
// prep (once): Qb = pad(Q)*(1/N), Pb = pad(P)+corner1 — bf16 swizzled. (proven)
// ---------------------------------------------------------------------------
__global__ __launch_bounds__(256) void prep_kernel(
    const float* __restrict__ ap, unsigned short* __restrict__ Qb,
    unsigned short* __restrict__ Pb)
{
    const int t = threadIdx.x;
    const float inv = 1.0f / 1023.0f;
    #pragma unroll
    for (int e = 0; e < 16; ++e) {
        const int p  = blockIdx.x * 4096 + e * 256 + t;   // 0 .. 2^19-1
        const int c  = (p & 63) * 2;
        const int r  = (p >> 6) & 127;
        const int h  = (p >> 13) & 7;
        const int isP = (p >> 16) & 1;
        const int l  = (p >> 17) & 3;
        const float* apl = ap + ((size_t)(l * H + h) * 2 + (isP ? 0 : 1)) * DM * DM;
        float v0, v1;
        if (!isP) {
            v0 = (r < DM && c     < DM) ? apl[r * DM + c] * inv     : 0.f;
            v1 = (r < DM && c + 1 < DM) ? apl[r * DM + c + 1] * inv : 0.f;
        } else {
            v0 = (r < DM && c     < DM) ? apl[r * DM + c]     : 0.f;
            v1 = (r < DM && c + 1 < DM) ? apl[r * DM + c + 1]
                 : ((r == DM && c + 1 == DM) ? 1.f : 0.f);
        }
        unsigned short* base = (isP ? Pb : Qb) + (size_t)(l * H + h) * DD;
        const int el = SW(r, c);
        ((unsigned int*)base)[el >> 1] =
            (unsigned int)f2bf(v0) | ((unsigned int)f2bf(v1) << 16);
    }
}

// ---------------------------------------------------------------------------
// gp: chunk Gram of Z0 via MFMA (round-9-proven: fp32 stage + transpose-
// convert + masked). grid (8, B) x 256. Output transposed (symmetric).
// ---------------------------------------------------------------------------
__global__ __launch_bounds__(256) void gp_kernel(
    const float* __restrict__ Z, float* __restrict__ Gp)
{
    const int c = blockIdx.x, b = blockIdx.y;
    const int t = threadIdx.x, lane = t & 63, w = t >> 6;

    __shared__ __align__(16) float Zs[128 * 128];          // 64 KB
    __shared__ __align__(16) unsigned short Zt[128 * 128]; // 32 KB

    const float* src = Z + ((size_t)b * NP1 + c * 128) * D;
    #pragma unroll
    for (int i = 0; i < 16; ++i)
        async16(src + (t + 256 * i) * 4, Zs + (t + 256 * i) * 4);
    __syncthreads();

    {
        const int d = t >> 1, half = t & 1;
        const int sft = (d & 7) << 3;
        #pragma unroll 4
        for (int tp = 0; tp < 32; ++tp) {
            const int tk = ((tp + d) & 31) * 2 + half * 64;
            float v0 = Zs[tk * 128 + d];
            float v1 = Zs[(tk + 1) * 128 + d];
            if (c == 7 && tk == 126) v1 = 0.f;   // key mask: token 1023
            ((unsigned int*)Zt)[(d * 128 + (tk ^ sft)) >> 1] =
                (unsigned int)f2bf(v0) | ((unsigned int)f2bf(v1) << 16);
        }
    }
    __syncthreads();

    f32x4 acc[2][8] = {};
    #pragma unroll
    for (int k0 = 0; k0 < 128; k0 += 32) {
        const bf16x8 a0 = fragAB(Zt, (w * 2 + 0) * 16, k0, lane);
        const bf16x8 a1 = fragAB(Zt, (w * 2 + 1) * 16, k0, lane);
        #pragma unroll
        for (int nt = 0; nt < 8; ++nt) {
            const bf16x8 bb = fragAB(Zt, nt * 16, k0, lane);
            acc[0][nt] = MFMA(a0, bb, acc[0][nt]);
            acc[1][nt] = MFMA(a1, bb, acc[1][nt]);
        }
    }

    float* Gb = Gp + ((size_t)(b * 8 + c)) * DD;
    #pragma unroll
    for (int m = 0; m < 2; ++m) {
        const int rg = (w * 2 + m) * 16 + ((lane >> 4) << 2);
        #pragma unroll
        for (int nt = 0; nt < 8; ++nt) {
            const int cg = nt * 16 + (lane & 15);
            *(f32x4*)&Gb[cg * 128 + rg] = acc[m][nt];   // transposed (symmetric)
        }
    }
}

// ---------------------------------------------------------------------------
// gred: G0 = sum_c Gp -> bf16 swizzled AND f32 row-major. grid (16, B) x 256.
// ---------------------------------------------------------------------------
__global__ __launch_bounds__(256) void gred_kernel(
    const float* __restrict__ Gp, unsigned short* __restrict__ Gbf,
    float* __restrict__ Gf)
{
    const int b = blockIdx.y;
    const int idx4 = blockIdx.x * 256 + threadIdx.x;   // 0..4095
    float4 sum = make_float4(0.f, 0.f, 0.f, 0.f);
    #pragma unroll
    for (int c = 0; c < 8; ++c) {
        const float4 v = ((const float4*)Gp)[(size_t)(b * 8 + c) * 4096 + idx4];
        sum.x += v.x; sum.y += v.y; sum.z += v.z; sum.w += v.w;
    }
    ((float4*)Gf)[(size_t)b * 4096 + idx4] = sum;       // f32 row-major
    const int row = idx4 >> 5;
    const int n0  = (idx4 & 31) * 4;
    const int el  = SW(row, n0);
    unsigned int* dst = (unsigned int*)(Gbf + (size_t)b * DD);
    dst[(el >> 1) + 0] = (unsigned int)f2bf(sum.x) | ((unsigned int)f2bf(sum.y) << 16);
    dst[(el >> 1) + 1] = (unsigned int)f2bf(sum.z) | ((unsigned int)f2bf(sum.w) << 16);
}

// ---------------------------------------------------------------------------
// heads: Spt[b][h] = (Qf_h @ G @ Pf_h^T)^T via U = G@Pf^T then S = Qf@U.
// grid (H, B) = 64 blocks x 256. LDS = 4 x 32 KB = 128 KB.
// ---------------------------------------------------------------------------
__global__ __launch_bounds__(256) void heads_kernel(
    const unsigned short* __restrict__ Qb, const unsigned short* __restrict__ Pb,
    const unsigned short* __restrict__ Gbf, unsigned short* __restrict__ Spt)
{
    const int h = blockIdx.x, b = blockIdx.y;
    const int t = threadIdx.x, lane = t & 63, w = t >> 6;

    __shared__ __align__(16) unsigned short Gs[DD];   // 32 KB
    __shared__ __align__(16) unsigned short Ps[DD];   // 32 KB
    __shared__ __align__(16) unsigned short Qs[DD];   // 32 KB
    __shared__ __align__(16) unsigned short Ub[DD];   // 32 KB (U^T)

    const unsigned short* gsrc = Gbf + (size_t)b * DD;
    #pragma unroll
    for (int i = 0; i < 8; ++i)
        async16((const char*)gsrc + (t + 256 * i) * 16, (char*)Gs + (t + 256 * i) * 16);
    const unsigned short* psrc = Pb + (size_t)h * DD;
    #pragma unroll
    for (int i = 0; i < 8; ++i)
        async16((const char*)psrc + (t + 256 * i) * 16, (char*)Ps + (t + 256 * i) * 16);
    const unsigned short* qsrc = Qb + (size_t)h * DD;
    #pragma unroll
    for (int i = 0; i < 8; ++i)
        async16((const char*)qsrc + (t + 256 * i) * 16, (char*)Qs + (t + 256 * i) * 16);

    // G+P done (Q's 8 newest may stay in flight)
    asm volatile("s_waitcnt vmcnt(8)" ::: "memory");
    __builtin_amdgcn_s_barrier();
    asm volatile("" ::: "memory");

    // U[j,i] = sum_m G[j,m] Pf[i,m]; wave w: j-tiles {2w,2w+1} x i 0..7
    f32x4 u[2][8] = {};
    #pragma unroll
    for (int k0 = 0; k0 < 128; k0 += 32) {
        const bf16x8 a0 = fragAB(Gs, (w * 2 + 0) * 16, k0, lane);
        const bf16x8 a1 = fragAB(Gs, (w * 2 + 1) * 16, k0, lane);
        #pragma unroll
        for (int i = 0; i < 8; ++i) {
            const bf16x8 bb = fragAB(Ps, i * 16, k0, lane);
            u[0][i] = MFMA(a0, bb, u[0][i]);
            u[1][i] = MFMA(a1, bb, u[1][i]);
        }
    }
    // transposed-packed: Ub = U^T row-major swizzled
    #pragma unroll
    for (int m = 0; m < 2; ++m) {
        const int rg0 = (w * 2 + m) * 16 + ((lane >> 4) << 2);
        #pragma unroll
        for (int i = 0; i < 8; ++i) {
            const int cg = i * 16 + (lane & 15);
            *(ushort4v*)&Ub[SW(cg, rg0)] = packbf(u[m][i]);
        }
    }
    __syncthreads();   // Ub visible; drains Qs loads

    // S[r,i] = sum_j Qf[r,j] U[j,i]; B-frag rows = Ub rows (U^T)
    f32x4 sv[2][8] = {};
    #pragma unroll
    for (int k0 = 0; k0 < 128; k0 += 32) {
        const bf16x8 a0 = fragAB(Qs, (w * 2 + 0) * 16, k0, lane);
        const bf16x8 a1 = fragAB(Qs, (w * 2 + 1) * 16, k0, lane);
        #pragma unroll
        for (int i = 0; i < 8; ++i) {
            const bf16x8 bb = fragAB(Ub, i * 16, k0, lane);
            sv[0][i] = MFMA(a0, bb, sv[0][i]);
            sv[1][i] = MFMA(a1, bb, sv[1][i]);
        }
    }
    // store S^T transposed-packed
    unsigned short* dst = Spt + (size_t)(b * H + h) * DD;
    #pragma unroll
    for (int m = 0; m < 2; ++m) {
        const int rg0 = (w * 2 + m) * 16 + ((lane >> 4) << 2);
        #pragma unroll
        for (int i = 0; i < 8; ++i) {
            const int cg = i * 16 + (lane & 15);
            *(ushort4v*)&dst[SW(cg, rg0)] = packbf(sv[m][i]);
        }
    }
}

// ---------------------------------------------------------------------------
// upd: St = sum_h Spt; X' = G + S^T G; G' = X' + X'S (fp32 C-init chain);
// R' = R + S + R S. grid (4 row-slices, B) = 32 blocks x 256. LDS 112 KB.
// G/R ping-pong (no in-dispatch read/write overlap).
// ---------------------------------------------------------------------------
__global__ __launch_bounds__(256) void upd_kernel(
    const unsigned short* __restrict__ Spt,
    const unsigned short* __restrict__ Gbf_in, const float* __restrict__ Gf_in,
    const unsigned short* __restrict__ Rb_in,
    unsigned short* __restrict__ Gbf_out, float* __restrict__ Gf_out,
    unsigned short* __restrict__ Rb_out, unsigned short* __restrict__ Rtb,
    int hasR)
{
    const int s = blockIdx.x, b = blockIdx.y;
    const int t = threadIdx.x, lane = t & 63, w = t >> 6;

    __shared__ __align__(16) unsigned short Gs[DD];       // 32 KB bf16 swz
    __shared__ __align__(16) unsigned short Sts[DD];      // 32 KB bf16 swz (S^T)
    __shared__ __align__(16) float Gfs[32 * 128];         // 16 KB f32 G rows slice
    __shared__ __align__(16) float Xf[32 * 128];          // 16 KB f32 X' slice
    __shared__ __align__(16) unsigned short Xb[32 * 128]; // 8 KB bf16 swz X'
    __shared__ __align__(16) unsigned short Rbs[32 * 128];// 8 KB bf16 swz R slice

    // async staging
    const unsigned short* gsrc = Gbf_in + (size_t)b * DD;
    #pragma unroll
    for (int i = 0; i < 8; ++i)
        async16((const char*)gsrc + (t + 256 * i) * 16, (char*)Gs + (t + 256 * i) * 16);
    const float* gfsrc = Gf_in + (size_t)b * DD + s * 32 * 128;
    #pragma unroll
    for (int i = 0; i < 4; ++i)
        async16(gfsrc + (t + 256 * i) * 4, Gfs + (t + 256 * i) * 4);
    if (hasR) {
        const unsigned short* rsrc = Rb_in + (size_t)b * DD + s * 32 * 128;
        #pragma unroll
        for (int i = 0; i < 2; ++i)
            async16((const char*)rsrc + (t + 256 * i) * 16, (char*)Rbs + (t + 256 * i) * 16);
    }

    // stream-reduce 8 heads into Sts (f32 accumulate, bf16 store)
    {
        const unsigned short* sp0 = Spt + (size_t)b * H * DD;
        #pragma unroll 2
        for (int i = 0; i < 8; ++i) {
            const int ch = t + 256 * i;   // ushort8 chunk, 2048 total
            float a[8] = {0.f, 0.f, 0.f, 0.f, 0.f, 0.f, 0.f, 0.f};
            #pragma unroll
            for (int h = 0; h < 8; ++h) {
                const ushort8 uu = *(const ushort8*)&sp0[(size_t)h * DD + ch * 8];
                #pragma unroll
                for (int e = 0; e < 8; ++e) a[e] += bf2f(uu[e]);
            }
            ushort8 o;
            #pragma unroll
            for (int e = 0; e < 8; ++e) o[e] = f2bf(a[e]);
            *(ushort8*)&Sts[ch * 8] = o;
        }
    }
    __syncthreads();   // drains asyncs (older than Sp loads) + Sts visible

    // ---- X' = G + S^T G (rows slice). A = Sts rows (global), B = Gs rows ----
    f32x4 acc[2][2];
    #pragma unroll
    for (int m = 0; m < 2; ++m) {
        #pragma unroll
        for (int nl = 0; nl < 2; ++nl) {
            const int cg  = (w * 2 + nl) * 16 + (lane & 15);
            const int rl0 = m * 16 + ((lane >> 4) << 2);
            #pragma unroll
            for (int j = 0; j < 4; ++j) acc[m][nl][j] = Gfs[(rl0 + j) * 128 + cg];
        }
    }
    #pragma unroll
    for (int k0 = 0; k0 < 128; k0 += 32) {
        const bf16x8 a0 = fragAB(Sts, s * 32,      k0, lane);
        const bf16x8 a1 = fragAB(Sts, s * 32 + 16, k0, lane);
        const bf16x8 b0 = fragAB(Gs, (w * 2 + 0) * 16, k0, lane);
        const bf16x8 b1 = fragAB(Gs, (w * 2 + 1) * 16, k0, lane);
        acc[0][0] = MFMA(a0, b0, acc[0][0]);
        acc[0][1] = MFMA(a0, b1, acc[0][1]);
        acc[1][0] = MFMA(a1, b0, acc[1][0]);
        acc[1][1] = MFMA(a1, b1, acc[1][1]);
    }
    #pragma unroll
    for (int m = 0; m < 2; ++m) {
        #pragma unroll
        for (int nl = 0; nl < 2; ++nl) {
            const int cg  = (w * 2 + nl) * 16 + (lane & 15);
            const int rl0 = m * 16 + ((lane >> 4) << 2);
            #pragma unroll
            for (int j = 0; j < 4; ++j) {
                Xf[(rl0 + j) * 128 + cg] = acc[m][nl][j];
                Xb[SW(rl0 + j, cg)]      = f2bf(acc[m][nl][j]);
            }
        }
    }
    __syncthreads();

    // ---- G' = X' + X' S. A = Xb rows (local), B = Sts rows, C = Xf ----
    f32x4 gacc[2][2];
    #pragma unroll
    for (int m = 0; m < 2; ++m) {
        #pragma unroll
        for (int nl = 0; nl < 2; ++nl) {
            const int cg  = (w * 2 + nl) * 16 + (lane & 15);
            const int rl0 = m * 16 + ((lane >> 4) << 2);
            #pragma unroll
            for (int j = 0; j < 4; ++j) gacc[m][nl][j] = Xf[(rl0 + j) * 128 + cg];
        }
    }
    #pragma unroll
    for (int k0 = 0; k0 < 128; k0 += 32) {
        const bf16x8 a0 = fragAB(Xb, 0,  k0, lane);
        const bf16x8 a1 = fragAB(Xb, 16, k0, lane);
        const bf16x8 b0 = fragAB(Sts, (w * 2 + 0) * 16, k0, lane);
        const bf16x8 b1 = fragAB(Sts, (w * 2 + 1) * 16, k0, lane);
        gacc[0][0] = MFMA(a0, b0, gacc[0][0]);
        gacc[0][1] = MFMA(a0, b1, gacc[0][1]);
        gacc[1][0] = MFMA(a1, b0, gacc[1][0]);
        gacc[1][1] = MFMA(a1, b1, gacc[1][1]);
    }
    // stores: transposed-packed (G' symmetric)
    #pragma unroll
    for (int m = 0; m < 2; ++m) {
        #pragma unroll
        for (int nl = 0; nl < 2; ++nl) {
            const int cg  = (w * 2 + nl) * 16 + (lane & 15);
            const int rg0 = s * 32 + m * 16 + ((lane >> 4) << 2);
            *(f32x4*)&Gf_out[(size_t)b * DD + cg * 128 + rg0] = gacc[m][nl];
            *(ushort4v*)&Gbf_out[(size_t)b * DD + SW(cg, rg0)] = packbf(gacc[m][nl]);
        }
    }

    // ---- R' = R + S + R S (rows slice). A = Rbs rows, B = Sts rows ----
    f32x4 racc[2][2];
    #pragma unroll
    for (int m = 0; m < 2; ++m) {
        #pragma unroll
        for (int nl = 0; nl < 2; ++nl) {
            const int cg  = (w * 2 + nl) * 16 + (lane & 15);
            const int rl0 = m * 16 + ((lane >> 4) << 2);
            #pragma unroll
            for (int j = 0; j < 4; ++j) {
                float c0 = bf2f(Sts[SW(cg, s * 32 + rl0 + j)]);   // S[r,c] = St[c][r]
                if (hasR) c0 += bf2f(Rbs[SW(rl0 + j, cg)]);
                racc[m][nl][j] = c0;
            }
        }
    }
    if (hasR) {
        #pragma unroll
        for (int k0 = 0; k0 < 128; k0 += 32) {
            const bf16x8 a0 = fragAB(Rbs, 0,  k0, lane);
            const bf16x8 a1 = fragAB(Rbs, 16, k0, lane);
            const bf16x8 b0 = fragAB(Sts, (w * 2 + 0) * 16, k0, lane);
            const bf16x8 b1 = fragAB(Sts, (w * 2 + 1) * 16, k0, lane);
            racc[0][0] = MFMA(a0, b0, racc[0][0]);
            racc[0][1] = MFMA(a0, b1, racc[0][1]);
            racc[1][0] = MFMA(a1, b0, racc[1][0]);
            racc[1][1] = MFMA(a1, b1, racc[1][1]);
        }
    }
    #pragma unroll
    for (int m = 0; m < 2; ++m) {
        #pragma unroll
        for (int nl = 0; nl < 2; ++nl) {
            const int cg  = (w * 2 + nl) * 16 + (lane & 15);
            const int rg0 = s * 32 + m * 16 + ((lane >> 4) << 2);
            const ushort4v v = packbf(racc[m][nl]);
            *(ushort4v*)&Rtb[(size_t)b * DD + SW(cg, rg0)] = v;   // R^T packed
            #pragma unroll
            for (int j = 0; j < 4; ++j)                            // R row-major scatter
                Rb_out[(size_t)b * DD + SW(rg0 + j, cg)] = v[j];
        }
    }
}

// ---------------------------------------------------------------------------
// zfinal: out = Z0 + Z0 @ R (B-frags = Rtb rows = R^T). grid (32, B) x 256.
// (round-10-proven z_kernel minus the Ztr emit)
// ---------------------------------------------------------------------------
__global__ __launch_bounds__(256) void zfinal_kernel(
    const float* __restrict__ Zin, const unsigned short* __restrict__ Rtb,
    float* __restrict__ Zout)
{
    const int sblk = blockIdx.x, b = blockIdx.y;
    const int t = threadIdx.x, lane = t & 63, w = t >> 6;

    __shared__ __align__(16) float Zs[32 * 128];            // 16 KB
    __shared__ __align__(16) unsigned short Zb[32 * 128];   // 8 KB
    __shared__ __align__(16) unsigned short Ss[DD];         // 32 KB (R^T swz)

    const float* zsrc = Zin + ((size_t)b * NP1 + sblk * 32) * D;
    #pragma unroll
    for (int i = 0; i < 4; ++i)
        async16(zsrc + (t + 256 * i) * 4, Zs + (t + 256 * i) * 4);
    const unsigned short* ssrc = Rtb + (size_t)b * DD;
    #pragma unroll
    for (int i = 0; i < 8; ++i)
        async16((const char*)ssrc + (t + 256 * i) * 16, (char*)Ss + (t + 256 * i) * 16);

    asm volatile("s_waitcnt vmcnt(8)" ::: "memory");
    __builtin_amdgcn_s_barrier();
    asm volatile("" ::: "memory");

    {
        const int r = t >> 3, c0 = (t & 7) * 16;
        const int sft = (r & 7) << 3;
        #pragma unroll
        for (int cc = 0; cc < 16; cc += 2) {
            const float v0 = Zs[r * 128 + c0 + cc];
            const float v1 = Zs[r * 128 + c0 + cc + 1];
            ((unsigned int*)Zb)[(r * 128 + ((c0 + cc) ^ sft)) >> 1] =
                (unsigned int)f2bf(v0) | ((unsigned int)f2bf(v1) << 16);
        }
    }
    __syncthreads();

    f32x4 accR[2][2] = {};
    #pragma unroll
    for (int k0 = 0; k0 < 128; k0 += 32) {
        const bf16x8 a0 = fragAB(Zb, 0, k0, lane);
        const bf16x8 a1 = fragAB(Zb, 16, k0, lane);
        const bf16x8 b0 = fragAB(Ss, (w * 2 + 0) * 16, k0, lane);
        const bf16x8 b1 = fragAB(Ss, (w * 2 + 1) * 16, k0, lane);
        accR[0][0] = MFMA(a0, b0, accR[0][0]);
        accR[0][1] = MFMA(a0, b1, accR[0][1]);
        accR[1][0] = MFMA(a1, b0, accR[1][0]);
        accR[1][1] = MFMA(a1, b1, accR[1][1]);
    }

    #pragma unroll
    for (int m = 0; m < 2; ++m) {
        const int r0 = m * 16 + ((lane >> 4) << 2);
        #pragma unroll
        for (int nl = 0; nl < 2; ++nl) {
            const int cc = (w * 2 + nl) * 16 + (lane & 15);
            #pragma unroll
            for (int j = 0; j < 4; ++j) {
                const int r = r0 + j;
                Zout[((size_t)b * NP1 + sblk * 32 + r) * D + cc] =
                    Zs[r * 128 + cc] + accR[m][nl][j];
            }
        }
    }
}

// ---------------------------------------------------------------------------
extern "C" void kernel_launch(void* const* d_in, const int* in_sizes, int n_in,
                              void* d_out, int out_size, void* d_ws, size_t ws_size,
                              hipStream_t stream)
{
    const float* Z0 = (const float*)d_in[0];
    const float* ap = (const float*)d_in[1];
    float* out = (float*)d_out;
    float* ws  = (float*)d_ws;

    float* Gp  = ws + WS_GP;
    unsigned short* Spt = (unsigned short*)(ws + WS_SPT);
    unsigned short* Qb  = (unsigned short*)(ws + WS_QB);
    unsigned short* Pb  = (unsigned short*)(ws + WS_PB);
    unsigned short* Gbf = (unsigned short*)(ws + WS_GBF);
    float* Gf           = ws + WS_GF;
    unsigned short* Rb  = (unsigned short*)(ws + WS_RB);
    unsigned short* Rtb = (unsigned short*)(ws + WS_RTB);

    hipLaunchKernelGGL(prep_kernel, dim3(128),  dim3(256), 0, stream, ap, Qb, Pb);
    hipLaunchKernelGGL(gp_kernel,   dim3(8, B), dim3(256), 0, stream, Z0, Gp);
    hipLaunchKernelGGL(gred_kernel, dim3(16, B), dim3(256), 0, stream, Gp, Gbf, Gf);

    for (int l = 0; l < NL; ++l) {
        const int pi = l & 1, po = (l + 1) & 1;
        hipLaunchKernelGGL(heads_kernel, dim3(H, B), dim3(256), 0, stream,
                           Qb + (size_t)l * H * DD, Pb + (size_t)l * H * DD,
                           Gbf + (size_t)pi * B * DD, Spt);
        hipLaunchKernelGGL(upd_kernel, dim3(4, B), dim3(256), 0, stream,
                           Spt,
                           Gbf + (size_t)pi * B * DD, Gf + (size_t)pi * B * DD,
                           Rb + (size_t)pi * B * DD,
                           Gbf + (size_t)po * B * DD, Gf + (size_t)po * B * DD,
                           Rb + (size_t)po * B * DD, Rtb,
                           (l > 0) ? 1 : 0);
    }

    hipLaunchKernelGGL(zfinal_kernel, dim3(32, B), dim3(256), 0, stream, Z0, Rtb, out);
}